// Round 6
// baseline (444.440 us; speedup 1.0000x reference)
//
#include <hip/hip_runtime.h>
#include <cstdint>
#include <cstddef>

// SpectralGraphConv: B=8, N=1024, C_IN=C_OUT=64, K=4
//   z0 = x, z1 = L x, z_k = 2 L z_{k-1} - z_{k-2},  out = sum_k z_k @ theta[k]
//
// Round-6: ONE kernel, per-batch flag sync (not grid.sync - round 4 measured
// grid.sync at ~100us/sync). Stage-k WGs only need their batch's 64 WGs to
// finish stage k-1 -> device-scope atomic arrival counters + spin, valid
// because grid(512) == co-resident capacity (2 WG/CU, LDS-capped).
// Prep (x/theta transposes) embedded behind xflag; L read as f32 directly
// (verified round-3/4 DMA pipeline: D=5 LDS buffers, counted vmcnt, raw
// s_barrier, 16B-granule XOR swizzle). oacc in registers across stages.

typedef __bf16 bf16;
typedef bf16 bf16x8 __attribute__((ext_vector_type(8)));
typedef float f32x4 __attribute__((ext_vector_type(4)));

#define MFMA_BF16(a, b, c) __builtin_amdgcn_mfma_f32_16x16x32_bf16((a), (b), (c), 0, 0, 0)
#define WAITV(n) asm volatile("s_waitcnt vmcnt(" #n ")" ::: "memory")

__device__ __forceinline__ void dma16(const void* g, void* l) {
    __builtin_amdgcn_global_load_lds(
        (const __attribute__((address_space(1))) unsigned int*)g,
        (__attribute__((address_space(3))) unsigned int*)l, 16, 0, 0);
}

constexpr int D_ = 5, T_ = 16, KS_ = 64, LSTG_ = 12288;
constexpr int SMEM_BYTES = D_ * LSTG_ + 16 * 72 * 2;   // 63744 B -> 2 WG/CU

// ---- inter-WG sync primitives (device-scope, per G16) ----------------------
__device__ __forceinline__ void waitflag(int* p, int target, int t) {
    if (t == 0) {
        while (__hip_atomic_load(p, __ATOMIC_RELAXED, __HIP_MEMORY_SCOPE_AGENT) < target)
            __builtin_amdgcn_s_sleep(2);
    }
    __syncthreads();
    __threadfence();            // acquire: invalidate stale cached producer data
}
__device__ __forceinline__ void arrive(int* p, int t) {
    __threadfence();            // release: drain + make our stores visible
    __syncthreads();
    if (t == 0) atomicAdd(p, 1);
}

// ---------------------------------------------------------------------------
// stage body (VERBATIM round-4, verified absmax 0.25):
//   acc = L[b][m0:m0+16][:] @ zin[b] (transposed product, D-frag zT-oriented)
//   z = alpha*acc - zprev; zoutT written (stages 1,2); oacc += z @ theta[KTH]
//   (+ x @ theta[0] on stage 1). oacc lives in caller registers across stages.
// ---------------------------------------------------------------------------
template <int STAGE>
__device__ __forceinline__ void stage_body(
    int b, int m0, int t,
    const float* __restrict__ Lmat,
    const bf16* __restrict__ xb,       // [b][n][c] bf16
    const bf16* __restrict__ zinT,     // [b][c][n] bf16 (A operand)
    const bf16* __restrict__ zprevT,   // [b][c][n] bf16 (stages 2,3)
    const bf16* __restrict__ thT,      // [k][o][c] bf16
    bf16* __restrict__ zoutT,          // [b][c][n] bf16 (stages 1,2)
    unsigned char* smem,
    f32x4& oacc)
{
    const int w  = t >> 6;
    const int l  = t & 63;
    const int l15 = l & 15;
    const int lg  = l >> 4;
    const int c0  = w << 4;

    const float* Lrb = Lmat + ((size_t)(b * 1024 + m0)) * 1024;
    const bf16*  zb  = zinT + (size_t)b * 64 * 1024;

    // staging source constants (pre-swizzled: slot ^ (row&7))
    const int Lrow = t >> 4, Lslot = t & 15;
    const float* Lsrc = Lrb + (size_t)Lrow * 1024 + (Lslot ^ (Lrow & 7)) * 4;
    const int Zg0 = (w << 7) + l, Zg1 = Zg0 + 64;
    const int Zch0 = Zg0 >> 3, Zch1 = Zg1 >> 3;
    const bf16* Zsrc0 = zb + (size_t)Zch0 * 1024 + ((Zg0 & 7) ^ (Zch0 & 7)) * 8;
    const bf16* Zsrc1 = zb + (size_t)Zch1 * 1024 + ((Zg1 & 7) ^ (Zch1 & 7)) * 8;

    auto issue = [&](int k0, unsigned char* bufb) {
        dma16(Lsrc + k0, bufb + (w << 10));
        dma16(Zsrc0 + k0, bufb + 4096 + (w << 11));
        dma16(Zsrc1 + k0, bufb + 4096 + (w << 11) + 1024);
    };

    f32x4 acc = {0.f, 0.f, 0.f, 0.f};

    auto computeStep = [&](const unsigned char* bufb) {
        const float* Ll = (const float*)bufb;
        const bf16*  Zl = (const bf16*)(bufb + 4096);
        const int chan = c0 + l15;
        const int sA = chan & 7;
        bf16x8 a0 = *(const bf16x8*)(Zl + (((chan << 3) + (lg ^ sA)) << 3));
        bf16x8 a1 = *(const bf16x8*)(Zl + (((chan << 3) + ((4 + lg) ^ sA)) << 3));
        const int sB = l15 & 7;
        const float* Lr = Ll + (l15 << 6);
        f32x4 u0 = *(const f32x4*)(Lr + ((((lg << 1) | 0) ^ sB) << 2));
        f32x4 u1 = *(const f32x4*)(Lr + ((((lg << 1) | 1) ^ sB) << 2));
        f32x4 v0 = *(const f32x4*)(Lr + (((8 + ((lg << 1) | 0)) ^ sB) << 2));
        f32x4 v1 = *(const f32x4*)(Lr + (((8 + ((lg << 1) | 1)) ^ sB) << 2));
        bf16x8 b0, b1;
#pragma unroll
        for (int j = 0; j < 4; ++j) {
            b0[j] = (bf16)u0[j]; b0[4 + j] = (bf16)u1[j];
            b1[j] = (bf16)v0[j]; b1[4 + j] = (bf16)v1[j];
        }
        acc = MFMA_BF16(a0, b0, acc);
        acc = MFMA_BF16(a1, b1, acc);
    };

    // drain leftover vmcnt from previous stage's epilogue stores, then prologue
    WAITV(0);
    __builtin_amdgcn_sched_barrier(0);
#pragma unroll
    for (int s = 0; s < D_ - 1; ++s)
        issue(s * KS_, smem + s * LSTG_);

#pragma unroll
    for (int tt = 0; tt < T_; ++tt) {
        const int rem = (T_ - 1 - tt) < (D_ - 2) ? (T_ - 1 - tt) : (D_ - 2);
        if (rem >= 3)      WAITV(9);
        else if (rem == 2) WAITV(6);
        else if (rem == 1) WAITV(3);
        else               WAITV(0);
        __builtin_amdgcn_sched_barrier(0);
        __builtin_amdgcn_s_barrier();
        __builtin_amdgcn_sched_barrier(0);
        computeStep(smem + (tt % D_) * LSTG_);
        if (tt + D_ - 1 < T_)
            issue((tt + D_ - 1) * KS_, smem + ((tt + D_ - 1) % D_) * LSTG_);
    }

    // ---- epilogue: z = alpha*acc - zprev; D frag = (c=c0+lg*4+r, m=m0+l15) ----
    bf16 (*zbuf)[72] = (bf16(*)[72])(smem + D_ * LSTG_);
    const int cr = c0 + (lg << 2);
    const float alpha = (STAGE == 1) ? 1.0f : 2.0f;
    float zv[4];
#pragma unroll
    for (int r = 0; r < 4; ++r) {
        float zp = 0.f;
        if constexpr (STAGE >= 2)
            zp = (float)zprevT[(size_t)(b * 64 + cr + r) * 1024 + m0 + l15];
        zv[r] = alpha * acc[r] - zp;
    }
    if constexpr (STAGE <= 2) {
#pragma unroll
        for (int r = 0; r < 4; ++r)
            zoutT[(size_t)(b * 64 + cr + r) * 1024 + m0 + l15] = (bf16)zv[r];
    }
#pragma unroll
    for (int r = 0; r < 4; ++r)
        zbuf[l15][cr + r] = (bf16)zv[r];
    __syncthreads();

    // ---- theta phase: oacc += z @ theta[KTH] (+ x @ theta[0] on stage 1) ----
    const int o = (w << 4) + l15;
    if constexpr (STAGE == 1) {
#pragma unroll
        for (int ck = 0; ck < 2; ++ck) {   // x @ theta[0]
            bf16x8 ax = *reinterpret_cast<const bf16x8*>(
                xb + (size_t)(b * 1024 + m0 + l15) * 64 + ck * 32 + lg * 8);
            bf16x8 bt = *reinterpret_cast<const bf16x8*>(
                thT + (size_t)o * 64 + ck * 32 + lg * 8);
            oacc = MFMA_BF16(ax, bt, oacc);
        }
    }
    constexpr int KTH = (STAGE == 1) ? 1 : STAGE;
#pragma unroll
    for (int ck = 0; ck < 2; ++ck) {
        bf16x8 az = *reinterpret_cast<const bf16x8*>(&zbuf[l15][ck * 32 + lg * 8]);
        bf16x8 bt = *reinterpret_cast<const bf16x8*>(
            thT + (size_t)(KTH * 64 + o) * 64 + ck * 32 + lg * 8);
        oacc = MFMA_BF16(az, bt, oacc);
    }
    __syncthreads();   // zbuf reads done before smem reuse
}

// ---------------------------------------------------------------------------
// fused kernel: 512 WGs = 8 batches x 64 m-tiles; all co-resident (2 WG/CU).
// WG (b, local): local<16 -> prep x slice; local==16 && b<4 -> prep theta[b].
// flags (zeroed by hipMemsetAsync): xflag[8] | thflag | z1flag[8] | z2flag[8]
// ---------------------------------------------------------------------------
__global__ __launch_bounds__(256) void fused_kernel(
    const float* __restrict__ x, const float* __restrict__ Lmat,
    const float* __restrict__ theta,
    bf16* __restrict__ xT, bf16* __restrict__ xb, bf16* __restrict__ thT,
    bf16* __restrict__ z1T, bf16* __restrict__ z2T,
    float* __restrict__ out, int* __restrict__ flags)
{
    __shared__ __align__(16) unsigned char smem[SMEM_BYTES];
    const int bid = blockIdx.x;
    const int t = threadIdx.x;
    const int b = bid >> 6;
    const int local = bid & 63;
    const int m0 = local << 4;

    int* xflag  = flags + b;
    int* thflag = flags + 8;
    int* z1flag = flags + 9 + b;
    int* z2flag = flags + 17 + b;

    // ---- embedded prep (WG-uniform branch) -------------------------------
    if (local < 16 || (local == 16 && b < 4)) {
        const bool isx = local < 16;
        bf16 (*tile)[72] = reinterpret_cast<bf16(*)[72]>(smem);
        const int r = t >> 2;
        const int c0 = (t & 3) << 4;
        const float* src;
        bf16* dstT;
        int dst_ld;
        int n0 = 0;
        if (isx) {
            n0 = local << 6;
            src = x + (size_t)(b * 1024 + n0) * 64;
            dstT = xT + (size_t)b * 64 * 1024 + n0;
            dst_ld = 1024;
        } else {
            src = theta + (size_t)b * 4096;
            dstT = thT + (size_t)b * 4096;
            dst_ld = 64;
        }
        bf16x8 row0, row1;
#pragma unroll
        for (int j = 0; j < 16; j += 4) {
            f32x4 v = *reinterpret_cast<const f32x4*>(src + r * 64 + c0 + j);
#pragma unroll
            for (int i = 0; i < 4; ++i) {
                bf16 q = (bf16)v[i];
                tile[r][c0 + j + i] = q;
                if (j + i < 8) row0[j + i] = q; else row1[j + i - 8] = q;
            }
        }
        if (isx) {
            bf16* xr = xb + (size_t)(b * 1024 + n0 + r) * 64 + c0;
            *reinterpret_cast<bf16x8*>(xr) = row0;
            *reinterpret_cast<bf16x8*>(xr + 8) = row1;
        }
        __syncthreads();
        bf16x8 o0, o1;
#pragma unroll
        for (int j = 0; j < 8; ++j) { o0[j] = tile[c0 + j][r]; o1[j] = tile[c0 + 8 + j][r]; }
        *reinterpret_cast<bf16x8*>(dstT + (size_t)r * dst_ld + c0) = o0;
        *reinterpret_cast<bf16x8*>(dstT + (size_t)r * dst_ld + c0 + 8) = o1;
        __threadfence();
        __syncthreads();
        if (t == 0) atomicAdd(isx ? xflag : thflag, 1);
    }

    // ---- wait for this batch's prep + theta ------------------------------
    waitflag(xflag, 16, t);
    waitflag(thflag, 4, t);

    f32x4 oacc = {0.f, 0.f, 0.f, 0.f};

    stage_body<1>(b, m0, t, Lmat, xb, xT, nullptr, thT, z1T, smem, oacc);
    arrive(z1flag, t);
    waitflag(z1flag, 64, t);
    stage_body<2>(b, m0, t, Lmat, xb, z1T, xT, thT, z2T, smem, oacc);
    arrive(z2flag, t);
    waitflag(z2flag, 64, t);
    stage_body<3>(b, m0, t, Lmat, xb, z2T, z1T, thT, nullptr, smem, oacc);

    // ---- out write (once) -------------------------------------------------
    const int w = t >> 6, l = t & 63, l15 = l & 15, lg = l >> 4;
    const int o = (w << 4) + l15;
#pragma unroll
    for (int r = 0; r < 4; ++r)
        out[(size_t)(b * 1024 + m0 + lg * 4 + r) * 64 + o] = oacc[r];
}

// ---------------------------------------------------------------------------
extern "C" void kernel_launch(void* const* d_in, const int* in_sizes, int n_in,
                              void* d_out, int out_size, void* d_ws, size_t ws_size,
                              hipStream_t stream)
{
    const float* x  = (const float*)d_in[0];    // [8,1024,64]
    const float* L  = (const float*)d_in[1];    // [8,1024,1024]
    const float* th = (const float*)d_in[2];    // [4,64,64]
    float* out = (float*)d_out;                 // [8,1024,64]

    // ws (bf16): xT | xb | z1T | z2T | thT | flags
    bf16* xT  = (bf16*)d_ws;
    bf16* xb  = xT  + (size_t)8 * 64 * 1024;
    bf16* z1T = xb  + (size_t)8 * 64 * 1024;
    bf16* z2T = z1T + (size_t)8 * 64 * 1024;
    bf16* thT = z2T + (size_t)8 * 64 * 1024;
    int*  flags = (int*)((char*)d_ws + 4 * 1048576 + 32768);

    hipMemsetAsync(flags, 0, 128, stream);
    void* args_unused = nullptr; (void)args_unused; (void)ws_size; (void)in_sizes; (void)n_in; (void)out_size;
    fused_kernel<<<dim3(512), dim3(256), 0, stream>>>(
        x, L, th, xT, xb, thT, z1T, z2T, out, flags);
}

// Round 7
// 99.731 us; speedup vs baseline: 4.4564x; 4.4564x over previous
//
#include <hip/hip_runtime.h>
#include <cstdint>
#include <cstddef>

// SpectralGraphConv: B=8, N=1024, C_IN=C_OUT=64, K=4
//   z0 = x, z1 = L x, z_k = 2 L z_{k-1} - z_{k-2},  out = sum_k z_k @ theta[k]
//
// Round-7: 4 plain dispatches (in-kernel cross-WG sync measured at ~100us/
// boundary on this chip - rounds 4/6). Round-5 base (Lb bf16 conversion in
// prep) + stage geometry change: m-tile 32, 8-wave WGs, 256 WGs = 1 WG/CU.
//  - staged bytes/stage 80MB -> 48MB (zT re-read halves), 2 DMA insts/wave/step
//  - D=5 LDS buffers (60KB), counted vmcnt (E=2 events/step: 6/4/2/0)
//  - epilogue zbuf aliased onto staging buffer 1 (dead after last barrier)
// Fragment/swizzle/epilogue math identical to verified round-5 (absmax 0.25),
// re-indexed for 8 waves: wave w = (chan-group w&3, m-half w>>2).

typedef __bf16 bf16;
typedef bf16 bf16x8 __attribute__((ext_vector_type(8)));
typedef float f32x4 __attribute__((ext_vector_type(4)));

#define MFMA_BF16(a, b, c) __builtin_amdgcn_mfma_f32_16x16x32_bf16((a), (b), (c), 0, 0, 0)
#define WAITV(n) asm volatile("s_waitcnt vmcnt(" #n ")" ::: "memory")

__device__ __forceinline__ void dma16(const void* g, void* l) {
    __builtin_amdgcn_global_load_lds(
        (const __attribute__((address_space(1))) unsigned int*)g,
        (__attribute__((address_space(3))) unsigned int*)l, 16, 0, 0);
}

// ---------------------------------------------------------------------------
// prep: blocks 0..127: x -> xT (bf16 [b][c][n]) + xb (bf16 [b][n][c])
//       blocks 128..131: theta -> thT (bf16 [k][o][c])
//       blocks 132..1155: L f32 -> Lb bf16 (row-major, streaming, 16B stores)
// ---------------------------------------------------------------------------
__global__ __launch_bounds__(256) void prep_kernel(const float* __restrict__ x,
                                                   const float* __restrict__ theta,
                                                   const float* __restrict__ Lmat,
                                                   bf16* __restrict__ xT,
                                                   bf16* __restrict__ xb,
                                                   bf16* __restrict__ thT,
                                                   bf16* __restrict__ Lb)
{
    const int bid = blockIdx.x;
    const int t = threadIdx.x;

    if (bid >= 132) {                       // ---- L f32 -> bf16 streaming ----
        constexpr int CHUNKS = (8 * 1024 * 1024) / 8;   // 8-f32 chunks
        const int stride = (1156 - 132) * 256;
        for (int idx = (bid - 132) * 256 + t; idx < CHUNKS; idx += stride) {
            f32x4 v0 = ((const f32x4*)Lmat)[2 * idx];
            f32x4 v1 = ((const f32x4*)Lmat)[2 * idx + 1];
            bf16x8 q;
#pragma unroll
            for (int i = 0; i < 4; ++i) { q[i] = (bf16)v0[i]; q[4 + i] = (bf16)v1[i]; }
            ((bf16x8*)Lb)[idx] = q;
        }
        return;
    }

    __shared__ bf16 tile[64][72];
    const int r = t >> 2;
    const int c0 = (t & 3) << 4;
    const float* src;
    bf16* dstT;
    int dst_ld;
    const bool isx = bid < 128;
    int b = 0, n0 = 0;
    if (isx) {
        b = bid >> 4; n0 = (bid & 15) << 6;
        src = x + (size_t)(b * 1024 + n0) * 64;
        dstT = xT + (size_t)b * 64 * 1024 + n0;
        dst_ld = 1024;
    } else {
        const int k = bid - 128;
        src = theta + (size_t)k * 4096;
        dstT = thT + (size_t)k * 4096;
        dst_ld = 64;
    }

    bf16x8 row0, row1;
#pragma unroll
    for (int j = 0; j < 16; j += 4) {
        f32x4 v = *reinterpret_cast<const f32x4*>(src + r * 64 + c0 + j);
#pragma unroll
        for (int i = 0; i < 4; ++i) {
            bf16 q = (bf16)v[i];
            tile[r][c0 + j + i] = q;
            if (j + i < 8) row0[j + i] = q; else row1[j + i - 8] = q;
        }
    }
    if (isx) {
        bf16* xr = xb + (size_t)(b * 1024 + n0 + r) * 64 + c0;
        *reinterpret_cast<bf16x8*>(xr) = row0;
        *reinterpret_cast<bf16x8*>(xr + 8) = row1;
    }
    __syncthreads();
    bf16x8 o0, o1;
#pragma unroll
    for (int j = 0; j < 8; ++j) { o0[j] = tile[c0 + j][r]; o1[j] = tile[c0 + 8 + j][r]; }
    *reinterpret_cast<bf16x8*>(dstT + (size_t)r * dst_ld + c0) = o0;
    *reinterpret_cast<bf16x8*>(dstT + (size_t)r * dst_ld + c0 + 8) = o1;
}

// ---------------------------------------------------------------------------
// stage kernel: WG = 8 waves (512 thr), one 32-row m-tile of one batch.
// wave w: chan-group wq=w&3 (chans [16wq,16wq+16)), m-half h=w>>2.
// LDS per step buffer: Lb tile 32x64 bf16 (4KB) + zT tile 64x64 bf16 (8KB),
// 16B-granule XOR swizzle (slot ^ (row&7)), D=5 buffers = 60KB.
// ---------------------------------------------------------------------------
template <int STAGE>
__global__ __launch_bounds__(512) void stage_kernel(
    const bf16* __restrict__ Lb,       // [b][m][k] bf16
    const bf16* __restrict__ xb,       // [b][n][c] bf16 (stage 1 theta phase)
    const bf16* __restrict__ zinT,     // [b][c][n] bf16 (A operand)
    const bf16* __restrict__ zprevT,   // [b][c][n] bf16 (subtract, stages 2,3)
    const bf16* __restrict__ thT,      // [k][o][c] bf16
    bf16* __restrict__ zoutT,          // [b][c][n] bf16 (stages 1,2)
    float* __restrict__ out)           // [b][n][o] f32
{
    constexpr int D = 5, T = 16, KS = 64, LSTG = 12288;
    __shared__ __align__(16) unsigned char smem[D * LSTG];   // 61440 B

    const int bid = blockIdx.x;
    const int b  = bid >> 5;
    const int m0 = (bid & 31) << 5;
    const int t  = threadIdx.x;
    const int w  = t >> 6;             // 0..7
    const int l  = t & 63;
    const int l15 = l & 15;
    const int lg  = l >> 4;
    const int wq  = w & 3;             // chan group
    const int h   = w >> 2;            // m half

    const bf16* Lrb = Lb + ((size_t)(b * 1024 + m0)) * 1024;
    const bf16* zb  = zinT + (size_t)b * 64 * 1024;

    // --- staging source constants (pre-swizzled: slot ^ (row&7)) ---
    // L: 256 granules/step (32 rows x 8); wave w lanes l<32: g = w*32 + l.
    const int Lg = (w << 5) + (l & 31);
    const int Lrow = Lg >> 3, Lslot = Lg & 7;
    const bf16* Lsrc = Lrb + (size_t)Lrow * 1024 + (Lslot ^ (Lrow & 7)) * 8;
    // Z: 512 granules/step (64 chans x 8); wave w: g = w*64 + l.
    const int Zg = (w << 6) + l;
    const int Zch = Zg >> 3;
    const bf16* Zsrc = zb + (size_t)Zch * 1024 + ((Zg & 7) ^ (Zch & 7)) * 8;

    auto issue = [&](int k0, unsigned char* bufb) {
        dma16(Zsrc + k0, bufb + 4096 + (w << 10));   // Z full wave
        if (l < 32)                                   // L half wave (exec-masked)
            dma16(Lsrc + k0, bufb + (w << 9));
    };

    f32x4 acc = {0.f, 0.f, 0.f, 0.f};

    auto computeStep = [&](const unsigned char* bufb) {
        const bf16* Ll = (const bf16*)bufb;
        const bf16* Zl = (const bf16*)(bufb + 4096);
        const int chan = (wq << 4) + l15;
        const int sA = chan & 7;
        bf16x8 a0 = *(const bf16x8*)(Zl + (((chan << 3) + (lg ^ sA)) << 3));
        bf16x8 a1 = *(const bf16x8*)(Zl + (((chan << 3) + ((4 + lg) ^ sA)) << 3));
        const int mrow = (h << 4) + l15;
        const int sB = mrow & 7;
        bf16x8 b0 = *(const bf16x8*)(Ll + (((mrow << 3) + (lg ^ sB)) << 3));
        bf16x8 b1 = *(const bf16x8*)(Ll + (((mrow << 3) + ((4 + lg) ^ sB)) << 3));
        acc = MFMA_BF16(a0, b0, acc);
        acc = MFMA_BF16(a1, b1, acc);
    };

    // --- prologue: D-1 steps in flight (2 insts/wave/step) ---
#pragma unroll
    for (int s = 0; s < D - 1; ++s)
        issue(s * KS, smem + s * LSTG);

    // --- main loop: counted vmcnt, E=2 events/step ---
#pragma unroll
    for (int tt = 0; tt < T; ++tt) {
        const int rem = ((T - tt) < (D - 1) ? (T - tt) : (D - 1)) - 1;
        if (rem >= 3)      WAITV(6);
        else if (rem == 2) WAITV(4);
        else if (rem == 1) WAITV(2);
        else               WAITV(0);
        __builtin_amdgcn_sched_barrier(0);
        __builtin_amdgcn_s_barrier();
        __builtin_amdgcn_sched_barrier(0);
        computeStep(smem + (tt % D) * LSTG);
        if (tt + D - 1 < T)
            issue((tt + D - 1) * KS, smem + ((tt + D - 1) % D) * LSTG);
    }

    // ---- epilogue: z = alpha*acc - zprev ----------------------------------
    // D frag: chan = wq*16 + lg*4 + r, m-col = m0 + h*16 + l15.
    // zbuf aliased onto staging buffer 1 (last DMA'd step 11, last read tt=11;
    // all waves past barrier@12 have completed those reads -> safe after loop).
    bf16 (*zbuf)[72] = (bf16(*)[72])(smem + LSTG);
    const int cr   = (wq << 4) + (lg << 2);
    const int mcol = m0 + (h << 4) + l15;
    const float alpha = (STAGE == 1) ? 1.0f : 2.0f;
    float zv[4];
#pragma unroll
    for (int r = 0; r < 4; ++r) {
        float zp = 0.f;
        if constexpr (STAGE >= 2)
            zp = (float)zprevT[(size_t)(b * 64 + cr + r) * 1024 + mcol];
        zv[r] = alpha * acc[r] - zp;
    }
    if constexpr (STAGE <= 2) {
#pragma unroll
        for (int r = 0; r < 4; ++r)
            zoutT[(size_t)(b * 64 + cr + r) * 1024 + mcol] = (bf16)zv[r];
    }
#pragma unroll
    for (int r = 0; r < 4; ++r)
        zbuf[(h << 4) + l15][cr + r] = (bf16)zv[r];
    __syncthreads();

    // ---- theta phase: out(+)= z @ theta[k]  (+ x @ theta[0] on stage 1) ----
    const int o = (wq << 4) + l15;          // output channel column
    const int mrowA = m0 + (h << 4) + l15;  // A-frag row (lane l15)
    f32x4 oacc;
    if constexpr (STAGE == 1) {
        oacc = (f32x4){0.f, 0.f, 0.f, 0.f};
#pragma unroll
        for (int ck = 0; ck < 2; ++ck) {    // x @ theta[0]
            bf16x8 ax = *reinterpret_cast<const bf16x8*>(
                xb + (size_t)(b * 1024 + mrowA) * 64 + ck * 32 + lg * 8);
            bf16x8 bt = *reinterpret_cast<const bf16x8*>(
                thT + (size_t)o * 64 + ck * 32 + lg * 8);
            oacc = MFMA_BF16(ax, bt, oacc);
        }
    } else {
#pragma unroll
        for (int r = 0; r < 4; ++r)
            oacc[r] = out[(size_t)(b * 1024 + m0 + (h << 4) + lg * 4 + r) * 64 + o];
    }
    constexpr int KTH = (STAGE == 1) ? 1 : STAGE;
#pragma unroll
    for (int ck = 0; ck < 2; ++ck) {
        bf16x8 az = *reinterpret_cast<const bf16x8*>(
            &zbuf[(h << 4) + l15][ck * 32 + lg * 8]);
        bf16x8 bt = *reinterpret_cast<const bf16x8*>(
            thT + (size_t)(KTH * 64 + o) * 64 + ck * 32 + lg * 8);
        oacc = MFMA_BF16(az, bt, oacc);
    }
#pragma unroll
    for (int r = 0; r < 4; ++r)
        out[(size_t)(b * 1024 + m0 + (h << 4) + lg * 4 + r) * 64 + o] = oacc[r];
}

// ---------------------------------------------------------------------------
extern "C" void kernel_launch(void* const* d_in, const int* in_sizes, int n_in,
                              void* d_out, int out_size, void* d_ws, size_t ws_size,
                              hipStream_t stream)
{
    const float* x  = (const float*)d_in[0];    // [8,1024,64]
    const float* L  = (const float*)d_in[1];    // [8,1024,1024]
    const float* th = (const float*)d_in[2];    // [4,64,64]
    float* out = (float*)d_out;                 // [8,1024,64]

    // ws (bf16): xT | xb | z1T | z2T | thT | Lb  (~20 MB)
    bf16* xT  = (bf16*)d_ws;
    bf16* xb  = xT  + (size_t)8 * 64 * 1024;
    bf16* z1T = xb  + (size_t)8 * 64 * 1024;
    bf16* z2T = z1T + (size_t)8 * 64 * 1024;
    bf16* thT = z2T + (size_t)8 * 64 * 1024;
    bf16* Lb  = thT + (size_t)4 * 64 * 64;

    prep_kernel<<<dim3(1156), dim3(256), 0, stream>>>(x, th, L, xT, xb, thT, Lb);
    // stage 1: z1 = L x;            out  = x@th0 + z1@th1
    stage_kernel<1><<<dim3(256), dim3(512), 0, stream>>>(Lb, xb, xT, nullptr, thT, z1T, out);
    // stage 2: z2 = 2 L z1 - x;     out += z2@th2
    stage_kernel<2><<<dim3(256), dim3(512), 0, stream>>>(Lb, xb, z1T, xT, thT, z2T, out);
    // stage 3: z3 = 2 L z2 - z1;    out += z3@th3
    stage_kernel<3><<<dim3(256), dim3(512), 0, stream>>>(Lb, xb, z2T, z1T, thT, nullptr, out);
}